// Round 8
// baseline (98.506 us; speedup 1.0000x reference)
//
#include <hip/hip_runtime.h>
#include <stdint.h>

#define BB 4
#define NN 4096
#define CC 256
#define DD 32

typedef __bf16 bf16;
typedef bf16 bf16x4 __attribute__((ext_vector_type(4)));
typedef bf16 bf16x8 __attribute__((ext_vector_type(8)));
typedef float f32x4 __attribute__((ext_vector_type(4)));
typedef unsigned int u32x4 __attribute__((ext_vector_type(4)));

// ---------------- prepw: WT[320][256] = [Wq*log2e | Wk | Wv]^T (bf16) -------
// Wq pre-scaled by log2(e) so softmax can use native exp2 (v_exp_f32).
__global__ void prepw_kernel(const float* __restrict__ Wq,
                             const float* __restrict__ Wk,
                             const float* __restrict__ Wv,
                             bf16* __restrict__ WT)
{
    int i = blockIdx.x * 256 + threadIdx.x;
    if (i < 320 * 256) {
        int d = i >> 8, c = i & 255;
        float val;
        if (d < DD)          val = Wq[c * DD + d] * 1.4426950408889634f;
        else if (d < 2 * DD) val = Wk[c * DD + (d - DD)];
        else                 val = Wv[c * CC + (d - 2 * DD)];
        WT[i] = (bf16)val;
    }
}

// ---------------- proj: [q|k|v] = x @ [Wq|Wk|Wv], f32 x read + in-reg cast --
__global__ __launch_bounds__(256) void proj_kernel(
    const float* __restrict__ x, const bf16* __restrict__ WT,
    bf16* __restrict__ qb, bf16* __restrict__ kb, bf16* __restrict__ vt)
{
    int b = blockIdx.x >> 7, nt = blockIdx.x & 127;   // 128 tiles of 32 rows
    int n0 = nt << 5;
    int tid = threadIdx.x;
    int w = tid >> 6, lane = tid & 63;
    int lm = lane & 15, g = lane >> 4;
    int rw = w >> 1;    // row half
    int ch = w & 1;     // ct half

    f32x4 acc[10];
    f32x4 zero4 = {0.f, 0.f, 0.f, 0.f};
#pragma unroll
    for (int i = 0; i < 10; ++i) acc[i] = zero4;

    const float* xrow = x + ((size_t)(b * NN) + n0 + rw * 16 + lm) * CC;
    for (int kc = 0; kc < 8; ++kc) {
        f32x4 a0 = *(const f32x4*)(xrow + kc * 32 + g * 8);
        f32x4 a1 = *(const f32x4*)(xrow + kc * 32 + g * 8 + 4);
        bf16x8 a;
        a[0] = (bf16)a0[0]; a[1] = (bf16)a0[1]; a[2] = (bf16)a0[2]; a[3] = (bf16)a0[3];
        a[4] = (bf16)a1[0]; a[5] = (bf16)a1[1]; a[6] = (bf16)a1[2]; a[7] = (bf16)a1[3];
#pragma unroll
        for (int ct = 0; ct < 10; ++ct) {
            int ctg = ch * 10 + ct;
            bf16x8 wv = *(const bf16x8*)(WT + (ctg * 16 + lm) * 256 + kc * 32 + g * 8);
            acc[ct] = __builtin_amdgcn_mfma_f32_16x16x32_bf16(a, wv, acc[ct], 0, 0, 0);
        }
    }

#pragma unroll
    for (int ct = 0; ct < 10; ++ct) {
        int ctg = ch * 10 + ct;
        int col = ctg * 16 + lm;
        if (ctg < 4) {
#pragma unroll
            for (int r = 0; r < 4; ++r) {
                int n = n0 + rw * 16 + g * 4 + r;
                bf16 hv = (bf16)acc[ct][r];
                if (ctg < 2) qb[((size_t)(b * NN) + n) * DD + col] = hv;
                else         kb[((size_t)(b * NN) + n) * DD + (col - DD)] = hv;
            }
        } else {
            int c = col - 64;
            int tile = nt >> 1;
            int nbase = ((nt & 1) * 32 + rw * 16 + g * 4) ^ ((c & 7) << 3);
            bf16x4 pk;
            pk[0] = (bf16)acc[ct][0]; pk[1] = (bf16)acc[ct][1];
            pk[2] = (bf16)acc[ct][2]; pk[3] = (bf16)acc[ct][3];
            size_t off = (((size_t)(b * 64 + tile)) * 256 + c) * 64 + nbase;
            *(bf16x4*)(vt + off) = pk;
        }
    }
}

// ====== attn v8: producer/consumer wave specialization (v7 structure), =====
// ====== shfl_xor reduce (proven primitive; permlane asm was the v7 bug) ====
// Block: 512 threads (8 waves), 64 q-rows, full 4096 keys. Even waves =
// producers: QK^T (swapped mfma(K,Q)) for rows 16*(w>>1)..+15, softmax
// (shfl_xor 16/32 reduce, exp2 domain), P/alpha -> parity LDS. Odd waves =
// consumers: PV for ALL 64 rows x channel quarter, V in regs (dbuf). PV lags
// QK by 1 tile; one barrier per tile. Producer softmax runs concurrently
// with consumer MFMA bursts.

#define LOADK(KT_, KF) { \
    const bf16* kbase_ = kb + ((size_t)(b * NN) + (size_t)(KT_) * 64) * DD + g * 8; \
    KF[0] = *(const bf16x8*)(kbase_ + (lm +  0) * DD); \
    KF[1] = *(const bf16x8*)(kbase_ + (lm + 16) * DD); \
    KF[2] = *(const bf16x8*)(kbase_ + (lm + 32) * DD); \
    KF[3] = *(const bf16x8*)(kbase_ + (lm + 48) * DD); }

#define LOADV(KT_, VB) { \
    const bf16* vtile_ = vt + ((size_t)(b * 64 + (KT_))) * 16384; \
    _Pragma("unroll") \
    for (int ct_ = 0; ct_ < 4; ++ct_) { \
        int c_ = 64 * sub + 16 * ct_ + lm; \
        const bf16* vrow_ = vtile_ + c_ * 64; \
        int vsw_ = (c_ & 7) << 3; \
        VB[ct_][0] = *(const bf16x8*)(vrow_ + ((8 * g) ^ vsw_)); \
        VB[ct_][1] = *(const bf16x8*)(vrow_ + ((32 + 8 * g) ^ vsw_)); \
    } }

// consumer: PV for tile whose P/alpha live in LDS parity PRV_, V frags in VB
#define PVBLOCK(PRV_, VB) { \
    const float* alph_p = (const float*)(lds + 16384 + (PRV_) * 512); \
    const uint32_t* flg_p = (const uint32_t*)(lds + 16384 + (PRV_) * 512 + 256); \
    const unsigned char* Pp_ = lds + (PRV_) * 8192; \
    u32x4 fl_ = *(const u32x4*)flg_p; \
    if ((fl_[0] & fl_[1] & fl_[2] & fl_[3]) == 0u) { \
        _Pragma("unroll") for (int rt_ = 0; rt_ < 4; ++rt_) { \
            f32x4 a_ = *(const f32x4*)(alph_p + rt_ * 16 + 4 * g); \
            _Pragma("unroll") for (int ct_ = 0; ct_ < 4; ++ct_) { \
                acc[rt_][ct_][0] *= a_[0]; acc[rt_][ct_][1] *= a_[1]; \
                acc[rt_][ct_][2] *= a_[2]; acc[rt_][ct_][3] *= a_[3]; \
            } \
        } \
    } \
    int psw_ = (lm & 7) << 4; \
    __builtin_amdgcn_s_setprio(1); \
    _Pragma("unroll") for (int rt_ = 0; rt_ < 4; ++rt_) { \
        const unsigned char* pr_ = Pp_ + (rt_ * 16 + lm) * 128; \
        bf16x8 pa0_ = *(const bf16x8*)(pr_ + (( 0 + 16 * g) ^ psw_)); \
        bf16x8 pa1_ = *(const bf16x8*)(pr_ + ((64 + 16 * g) ^ psw_)); \
        _Pragma("unroll") for (int ct_ = 0; ct_ < 4; ++ct_) { \
            acc[rt_][ct_] = __builtin_amdgcn_mfma_f32_16x16x32_bf16(pa0_, VB[ct_][0], acc[rt_][ct_], 0, 0, 0); \
            acc[rt_][ct_] = __builtin_amdgcn_mfma_f32_16x16x32_bf16(pa1_, VB[ct_][1], acc[rt_][ct_], 0, 0, 0); \
        } \
    } \
    __builtin_amdgcn_s_setprio(0); \
}

// consumer step for tile T_: PV(T_-1), then refill VB with V(T_+1)
#define PVSTEP(T_, VB) { \
    PVBLOCK((((T_) - 1) & 1), VB); \
    int ktn_ = ((T_) + 1 < 64) ? (T_) + 1 : 63; \
    LOADV(ktn_, VB); }

// producer step for tile T_: QK, softmax, P/alpha/flag write, K prefetch
#define QKSTEP(T_, KF, KFN) { \
    const int cur_ = (T_) & 1; \
    f32x4 sv0 = __builtin_amdgcn_mfma_f32_16x16x32_bf16(KF[0], qf, zero4, 0, 0, 0); \
    f32x4 sv1 = __builtin_amdgcn_mfma_f32_16x16x32_bf16(KF[1], qf, zero4, 0, 0, 0); \
    f32x4 sv2 = __builtin_amdgcn_mfma_f32_16x16x32_bf16(KF[2], qf, zero4, 0, 0, 0); \
    f32x4 sv3 = __builtin_amdgcn_mfma_f32_16x16x32_bf16(KF[3], qf, zero4, 0, 0, 0); \
    int ktn_ = ((T_) + 1 < 64) ? (T_) + 1 : 63; \
    LOADK(ktn_, KFN); \
    float mx_ = fmaxf(fmaxf(fmaxf(sv0[0], sv0[1]), fmaxf(sv0[2], sv0[3])), \
                      fmaxf(fmaxf(sv1[0], sv1[1]), fmaxf(sv1[2], sv1[3]))); \
    mx_ = fmaxf(mx_, fmaxf(fmaxf(sv2[0], sv2[1]), fmaxf(sv2[2], sv2[3]))); \
    mx_ = fmaxf(mx_, fmaxf(fmaxf(sv3[0], sv3[1]), fmaxf(sv3[2], sv3[3]))); \
    mx_ = fmaxf(mx_, __shfl_xor(mx_, 16)); \
    mx_ = fmaxf(mx_, __shfl_xor(mx_, 32)); \
    float alpha_; \
    int wave_ok_ = __all(mx_ <= mrun + 11.5f); \
    if (!wave_ok_) { float mn_ = fmaxf(mrun, mx_); alpha_ = __builtin_exp2f(mrun - mn_); mrun = mn_; } \
    else alpha_ = 1.0f; \
    float ssum_; \
    { \
        _Pragma("unroll") for (int j_ = 0; j_ < 4; ++j_) sv0[j_] = __builtin_exp2f(sv0[j_] - mrun); \
        _Pragma("unroll") for (int j_ = 0; j_ < 4; ++j_) sv1[j_] = __builtin_exp2f(sv1[j_] - mrun); \
        _Pragma("unroll") for (int j_ = 0; j_ < 4; ++j_) sv2[j_] = __builtin_exp2f(sv2[j_] - mrun); \
        _Pragma("unroll") for (int j_ = 0; j_ < 4; ++j_) sv3[j_] = __builtin_exp2f(sv3[j_] - mrun); \
        f32x4 t_ = (sv0 + sv1) + (sv2 + sv3); \
        ssum_ = (t_[0] + t_[1]) + (t_[2] + t_[3]); \
        ssum_ += __shfl_xor(ssum_, 16); \
        ssum_ += __shfl_xor(ssum_, 32); \
    } \
    lrun = lrun * alpha_ + ssum_; \
    unsigned char* Pb_ = lds + cur_ * 8192; \
    { \
        int rb_ = (16 * sub + lm) * 128; \
        int sw_ = (lm & 7) << 4; \
        bf16x4 pk_; \
        pk_[0] = (bf16)sv0[0]; pk_[1] = (bf16)sv0[1]; pk_[2] = (bf16)sv0[2]; pk_[3] = (bf16)sv0[3]; \
        *(bf16x4*)(Pb_ + rb_ + (( 0 + 8 * g) ^ sw_)) = pk_; \
        pk_[0] = (bf16)sv1[0]; pk_[1] = (bf16)sv1[1]; pk_[2] = (bf16)sv1[2]; pk_[3] = (bf16)sv1[3]; \
        *(bf16x4*)(Pb_ + rb_ + ((32 + 8 * g) ^ sw_)) = pk_; \
        pk_[0] = (bf16)sv2[0]; pk_[1] = (bf16)sv2[1]; pk_[2] = (bf16)sv2[2]; pk_[3] = (bf16)sv2[3]; \
        *(bf16x4*)(Pb_ + rb_ + ((64 + 8 * g) ^ sw_)) = pk_; \
        pk_[0] = (bf16)sv3[0]; pk_[1] = (bf16)sv3[1]; pk_[2] = (bf16)sv3[2]; pk_[3] = (bf16)sv3[3]; \
        *(bf16x4*)(Pb_ + rb_ + ((96 + 8 * g) ^ sw_)) = pk_; \
    } \
    float* alph_ = (float*)(lds + 16384 + cur_ * 512); \
    uint32_t* flg_ = (uint32_t*)(lds + 16384 + cur_ * 512 + 256); \
    if (g == 0) alph_[16 * sub + lm] = alpha_; \
    if (lane == 0) flg_[sub] = (uint32_t)wave_ok_; \
    asm volatile("s_waitcnt lgkmcnt(0)" ::: "memory"); \
}

__global__ __launch_bounds__(512, 2) void attn_kernel(
    const bf16* __restrict__ qb, const bf16* __restrict__ kb,
    const bf16* __restrict__ vt, const float* __restrict__ x,
    const float* __restrict__ gamma, float* __restrict__ out)
{
    // 2 x 8KB P buffers + 2 x 512B meta (alphas f32[64] @+0, flags u32[4] @+256)
    __shared__ __align__(16) unsigned char lds[17408];
    int bid = blockIdx.x;
    // XCD-aware decode: batch b -> XCDs {2b,2b+1} so vt/kb stay L2-resident
    int xcd = bid & 7, slot = bid >> 3;          // 256 blocks: slot in [0,32)
    int b = xcd >> 1;
    int qt = (xcd & 1) * 32 + slot;              // [0,64)
    int n0 = qt << 6;
    int tid = threadIdx.x;
    int w = tid >> 6, lane = tid & 63;
    int lm = lane & 15, g = lane >> 4;
    int qk = (w & 1) == 0;       // even waves produce, odd consume
    int sub = w >> 1;            // producer: row block; consumer: chan quarter

    f32x4 zero4 = {0.f, 0.f, 0.f, 0.f};
    f32x4 acc[4][4];             // consumer: rows rt*16+4g+r, chans 64sub+16ct+lm
#pragma unroll
    for (int i = 0; i < 4; ++i)
#pragma unroll
        for (int j = 0; j < 4; ++j) acc[i][j] = zero4;
    float mrun = -1e30f, lrun = 0.f;

    bf16x8 qf{};
    bf16x8 kfA[4], kfB[4];
    bf16x8 vbA[4][2], vbB[4][2];

    if (qk) {
        qf = *(const bf16x8*)(qb + ((size_t)(b * NN) + n0 + sub * 16 + lm) * DD + g * 8);
        LOADK(0, kfA);
    } else {
        LOADV(0, vbA);
    }

    // tile 0: producers QK(0) -> parity 0; consumers just prefetch V(1)
    if (qk) { QKSTEP(0, kfA, kfB); }
    else    { LOADV(1, vbB); }
    __builtin_amdgcn_s_barrier();
    asm volatile("" ::: "memory");

    int kt = 1;
    while (kt <= 61) {
        if (qk) { QKSTEP(kt, kfB, kfA); } else { PVSTEP(kt, vbA); }
        __builtin_amdgcn_s_barrier();
        asm volatile("" ::: "memory");
        if (qk) { QKSTEP(kt + 1, kfA, kfB); } else { PVSTEP(kt + 1, vbB); }
        __builtin_amdgcn_s_barrier();
        asm volatile("" ::: "memory");
        kt += 2;
    }
    // kt == 63 (last producer tile)
    if (qk) { QKSTEP(63, kfB, kfA); } else { PVSTEP(63, vbA); }
    __builtin_amdgcn_s_barrier();
    asm volatile("" ::: "memory");

    // hand off per-row softmax denominators (producers -> consumers)
    float* lsh = (float*)(lds + 16384);   // overlaps parity-0 meta only
    if (qk && g == 0) lsh[16 * sub + lm] = lrun;
    asm volatile("s_waitcnt lgkmcnt(0)" ::: "memory");
    __builtin_amdgcn_s_barrier();
    asm volatile("" ::: "memory");

    if (!qk) {
        // trailing PV(63): P parity 1, V in vbB
        PVBLOCK(1, vbB);

        float gam = gamma[0];
#pragma unroll
        for (int rt = 0; rt < 4; ++rt) {
            f32x4 lv = *(const f32x4*)(lsh + rt * 16 + 4 * g);
            f32x4 inv;
            inv[0] = 1.f / lv[0]; inv[1] = 1.f / lv[1];
            inv[2] = 1.f / lv[2]; inv[3] = 1.f / lv[3];
#pragma unroll
            for (int ct = 0; ct < 4; ++ct) {
                int col = 64 * sub + 16 * ct + lm;
#pragma unroll
                for (int r = 0; r < 4; ++r) {
                    int n = n0 + rt * 16 + 4 * g + r;
                    size_t idx = ((size_t)(b * NN) + n) * CC + col;
                    out[idx] = x[idx] + gam * acc[rt][ct][r] * inv[r];
                }
            }
        }
    }
}

extern "C" void kernel_launch(void* const* d_in, const int* in_sizes, int n_in,
                              void* d_out, int out_size, void* d_ws, size_t ws_size,
                              hipStream_t stream)
{
    const float* x     = (const float*)d_in[0];
    const float* Wq    = (const float*)d_in[1];
    const float* Wk    = (const float*)d_in[2];
    const float* Wv    = (const float*)d_in[3];
    const float* gamma = (const float*)d_in[4];
    float* out = (float*)d_out;

    char* ws = (char*)d_ws;
    bf16* WT = (bf16*)(ws);                  //   163,840 B
    bf16* qb = (bf16*)(ws + 163840);         // 1,048,576 B
    bf16* kb = (bf16*)(ws + 1212416);        // 1,048,576 B
    bf16* vt = (bf16*)(ws + 2260992);        // 8,388,608 B  (end 10,649,600)

    hipLaunchKernelGGL(prepw_kernel, dim3(320), dim3(256), 0, stream,
                       Wq, Wk, Wv, WT);
    hipLaunchKernelGGL(proj_kernel, dim3(512), dim3(256), 0, stream,
                       x, WT, qb, kb, vt);
    hipLaunchKernelGGL(attn_kernel, dim3(256), dim3(512), 0, stream,
                       qb, kb, vt, x, gamma, out);
}